// Round 1
// baseline (223.992 us; speedup 1.0000x reference)
//
#include <hip/hip_runtime.h>

// MinGRU: gate/update GEMMs + chunked parallel linear-recurrence scan.
// B=8, T=4096, D=H=256. All fp32 this round (no fp32 MFMA on CDNA4; the
// GEMM runs on the vector ALU). Round-2 candidate: split-bf16 MFMA GEMM.

namespace {
constexpr int kB  = 8;
constexpr int kT  = 4096;
constexpr int kD  = 256;
constexpr int kH  = 256;
constexpr int kBT = kB * kT;
constexpr int kL  = 64;          // scan chunk length
constexpr int kNC = kT / kL;     // 64 chunks per sequence

constexpr int TM = 64;           // GEMM row tile
constexpr int TN = 64;           // GEMM col tile
constexpr int BK = 32;           // GEMM k tile
} // namespace

// ---------------------------------------------------------------------------
// Kernel A: z = x@Wz^T + bz ; u = x@Wh^T + bh ; a = 1-sigmoid(z) ; bb = sigmoid(z)*u
// Tiled fp32 GEMM, both weight matrices in one pass (x tile loaded once).
// LDS tiles stored k-major so inner-loop fragment reads are ds_read_b128.
// ---------------------------------------------------------------------------
__global__ __launch_bounds__(256)
void gemm_gate_update(const float* __restrict__ x,
                      const float* __restrict__ Wz,
                      const float* __restrict__ bz,
                      const float* __restrict__ Wh,
                      const float* __restrict__ bh,
                      float* __restrict__ a_ws,
                      float* __restrict__ bb_ws)
{
    // +4 pad keeps 16B alignment for float4 reads and breaks bank aliasing.
    __shared__ __align__(16) float As[BK][TM + 4];
    __shared__ __align__(16) float Zs[BK][TN + 4];
    __shared__ __align__(16) float Hs[BK][TN + 4];

    const int tid  = threadIdx.x;
    const int tx   = tid & 15;     // 16 col groups
    const int ty   = tid >> 4;     // 16 row groups
    const int row0 = blockIdx.x * TM;
    const int col0 = blockIdx.y * TN;

    float accZ[4][4] = {};
    float accU[4][4] = {};

    for (int k0 = 0; k0 < kD; k0 += BK) {
        // Stage tiles: 64x32 floats per tile = 512 float4; 256 threads x 2.
        #pragma unroll
        for (int l = 0; l < 2; ++l) {
            const int linear = tid + l * 256;
            const int r  = linear >> 3;          // 0..63 tile row
            const int kq = (linear & 7) << 2;    // 0,4,...,28 k offset
            const float4 xv = *(const float4*)(x  + (size_t)(row0 + r) * kD + k0 + kq);
            const float4 zv = *(const float4*)(Wz + (size_t)(col0 + r) * kD + k0 + kq);
            const float4 hv = *(const float4*)(Wh + (size_t)(col0 + r) * kD + k0 + kq);
            As[kq + 0][r] = xv.x; As[kq + 1][r] = xv.y; As[kq + 2][r] = xv.z; As[kq + 3][r] = xv.w;
            Zs[kq + 0][r] = zv.x; Zs[kq + 1][r] = zv.y; Zs[kq + 2][r] = zv.z; Zs[kq + 3][r] = zv.w;
            Hs[kq + 0][r] = hv.x; Hs[kq + 1][r] = hv.y; Hs[kq + 2][r] = hv.z; Hs[kq + 3][r] = hv.w;
        }
        __syncthreads();

        #pragma unroll
        for (int k = 0; k < BK; ++k) {
            const float4 av = *(const float4*)&As[k][ty * 4];
            const float4 zv = *(const float4*)&Zs[k][tx * 4];
            const float4 hv = *(const float4*)&Hs[k][tx * 4];
            const float aa[4] = {av.x, av.y, av.z, av.w};
            const float zz[4] = {zv.x, zv.y, zv.z, zv.w};
            const float hh[4] = {hv.x, hv.y, hv.z, hv.w};
            #pragma unroll
            for (int i = 0; i < 4; ++i) {
                #pragma unroll
                for (int j = 0; j < 4; ++j) {
                    accZ[i][j] = fmaf(aa[i], zz[j], accZ[i][j]);
                    accU[i][j] = fmaf(aa[i], hh[j], accU[i][j]);
                }
            }
        }
        __syncthreads();
    }

    // Epilogue: fused sigmoid; write a = 1-g, bb = g*u as float4.
    #pragma unroll
    for (int i = 0; i < 4; ++i) {
        const int row = row0 + ty * 4 + i;
        float4 av, bv;
        #pragma unroll
        for (int j = 0; j < 4; ++j) {
            const int col = col0 + tx * 4 + j;
            const float z = accZ[i][j] + bz[col];
            const float g = 1.0f / (1.0f + __expf(-z));
            const float u = accU[i][j] + bh[col];
            (&av.x)[j] = 1.0f - g;
            (&bv.x)[j] = g * u;
        }
        const size_t o = (size_t)row * kH + col0 + tx * 4;
        *(float4*)(a_ws  + o) = av;
        *(float4*)(bb_ws + o) = bv;
    }
}

// ---------------------------------------------------------------------------
// Kernel B: per-chunk affine composition. h_end = A*h_start + Bv over kL steps.
// One block per (b, chunk); one thread per h (reads coalesced across h).
// ---------------------------------------------------------------------------
__global__ __launch_bounds__(256)
void chunk_scan(const float* __restrict__ a_ws,
                const float* __restrict__ bb_ws,
                float* __restrict__ Asum,
                float* __restrict__ Bsum)
{
    const int c = blockIdx.x % kNC;
    const int b = blockIdx.x / kNC;
    const int h = threadIdx.x;

    float A  = 1.0f;
    float Bv = 0.0f;
    const size_t base = ((size_t)b * kT + (size_t)c * kL) * kH + h;
    #pragma unroll 8
    for (int t = 0; t < kL; ++t) {
        const float a  = a_ws [base + (size_t)t * kH];
        const float bb = bb_ws[base + (size_t)t * kH];
        Bv = fmaf(a, Bv, bb);
        A *= a;
    }
    const size_t o = ((size_t)b * kNC + c) * kH + h;
    Asum[o] = A;
    Bsum[o] = Bv;
}

// ---------------------------------------------------------------------------
// Kernel C: sequential combine over chunk summaries -> h at each chunk start.
// Tiny: 8 blocks x 256 threads x 64 iterations.
// ---------------------------------------------------------------------------
__global__ __launch_bounds__(256)
void chunk_combine(const float* __restrict__ h0,
                   const float* __restrict__ Asum,
                   const float* __restrict__ Bsum,
                   float* __restrict__ hstart)
{
    const int b = blockIdx.x;
    const int h = threadIdx.x;
    float hv = h0[(size_t)b * kH + h];
    #pragma unroll 8
    for (int c = 0; c < kNC; ++c) {
        const size_t idx = ((size_t)b * kNC + c) * kH + h;
        hstart[idx] = hv;
        hv = fmaf(Asum[idx], hv, Bsum[idx]);
    }
}

// ---------------------------------------------------------------------------
// Kernel D: apply the recurrence within each chunk from its known h_start and
// write the final outputs.
// ---------------------------------------------------------------------------
__global__ __launch_bounds__(256)
void apply_scan(const float* __restrict__ a_ws,
                const float* __restrict__ bb_ws,
                const float* __restrict__ hstart,
                float* __restrict__ out)
{
    const int c = blockIdx.x % kNC;
    const int b = blockIdx.x / kNC;
    const int h = threadIdx.x;

    float hv = hstart[((size_t)b * kNC + c) * kH + h];
    const size_t base = ((size_t)b * kT + (size_t)c * kL) * kH + h;
    #pragma unroll 8
    for (int t = 0; t < kL; ++t) {
        const float a  = a_ws [base + (size_t)t * kH];
        const float bb = bb_ws[base + (size_t)t * kH];
        hv = fmaf(a, hv, bb);
        out[base + (size_t)t * kH] = hv;
    }
}

extern "C" void kernel_launch(void* const* d_in, const int* in_sizes, int n_in,
                              void* d_out, int out_size, void* d_ws, size_t ws_size,
                              hipStream_t stream)
{
    const float* x  = (const float*)d_in[0];
    const float* h0 = (const float*)d_in[1];
    const float* Wz = (const float*)d_in[2];
    const float* bz = (const float*)d_in[3];
    const float* Wh = (const float*)d_in[4];
    const float* bh = (const float*)d_in[5];
    float* out = (float*)d_out;

    // Workspace carve-up (fp32): a(33.5MB) + bb(33.5MB) + 3 x 0.5MB summaries.
    float* a_ws   = (float*)d_ws;
    float* bb_ws  = a_ws  + (size_t)kBT * kH;
    float* Asum   = bb_ws + (size_t)kBT * kH;
    float* Bsum   = Asum  + (size_t)kB * kNC * kH;
    float* hstart = Bsum  + (size_t)kB * kNC * kH;

    gemm_gate_update<<<dim3(kBT / TM, kH / TN), 256, 0, stream>>>(
        x, Wz, bz, Wh, bh, a_ws, bb_ws);
    chunk_scan<<<kB * kNC, kH, 0, stream>>>(a_ws, bb_ws, Asum, Bsum);
    chunk_combine<<<kB, kH, 0, stream>>>(h0, Asum, Bsum, hstart);
    apply_scan<<<kB * kNC, kH, 0, stream>>>(a_ws, bb_ws, hstart, out);
}

// Round 2
// 153.382 us; speedup vs baseline: 1.4604x; 1.4604x over previous
//
#include <hip/hip_runtime.h>

// MinGRU: bf16-MFMA gate/update GEMM + chunked parallel linear-recurrence scan.
// B=8, T=4096, D=H=256.
// GEMM: C[row, h] for both Wz and Wh in one pass; inputs converted fp32->bf16
// inline during LDS staging; fp32 MFMA accumulate; fused sigmoid epilogue
// writes a = 1-g and bb = g*u in fp32 (keeps recurrence precision; threshold
// is bf16-level so one bf16 rounding in the GEMM inputs is the only loss).

namespace {
constexpr int kB  = 8;
constexpr int kT  = 4096;
constexpr int kD  = 256;
constexpr int kH  = 256;
constexpr int kBT = kB * kT;
constexpr int kL  = 32;          // scan chunk length (1024 blocks = 4/CU)
constexpr int kNC = kT / kL;     // 128 chunks per sequence

constexpr int TM  = 128;         // GEMM row tile
constexpr int TH  = 64;          // GEMM h-col tile (dual-W: 128 effective N)
constexpr int BK  = 64;          // GEMM k tile
constexpr int BKP = BK + 8;      // LDS row stride (ushorts): 144 B, kills excess conflicts
} // namespace

typedef short  s16x8 __attribute__((ext_vector_type(8)));
typedef short  s16x4 __attribute__((ext_vector_type(4)));
typedef float  f32x4 __attribute__((ext_vector_type(4)));

__device__ __forceinline__ short f2bf(float f) {
    union { float f; unsigned int u; } v; v.f = f;
    unsigned int r = v.u + 0x7fffu + ((v.u >> 16) & 1u);   // RNE
    return (short)(r >> 16);
}

// ---------------------------------------------------------------------------
// Kernel A: z = x@Wz^T + bz ; u = x@Wh^T + bh ; a = 1-sigmoid(z) ; bb = sigmoid(z)*u
// 128x64 block tile, dual weight matrices, bf16 MFMA 16x16x32.
// 4 waves: wave w covers rows 64*(w&1).. and h-cols 32*(w>>1)..
// ---------------------------------------------------------------------------
__global__ __launch_bounds__(256)
void gemm_gate_update(const float* __restrict__ x,
                      const float* __restrict__ Wz,
                      const float* __restrict__ bz,
                      const float* __restrict__ Wh,
                      const float* __restrict__ bh,
                      float* __restrict__ a_ws,
                      float* __restrict__ bb_ws)
{
    __shared__ unsigned short Xs [TM][BKP];
    __shared__ unsigned short Wzs[TH][BKP];
    __shared__ unsigned short Whs[TH][BKP];

    const int tid  = threadIdx.x;
    const int lane = tid & 63;
    const int wv   = tid >> 6;
    const int ln15 = lane & 15;
    const int quad = lane >> 4;
    const int wr0  = (wv & 1) * 64;    // wave row offset within tile
    const int wc0  = (wv >> 1) * 32;   // wave h-col offset within tile
    const int row0 = blockIdx.y * TM;
    const int col0 = blockIdx.x * TH;

    f32x4 accZ[4][2] = {};
    f32x4 accU[4][2] = {};

    for (int k0 = 0; k0 < kD; k0 += BK) {
        // ---- stage x tile: 128 rows x 64 k (fp32 -> bf16). 2048 float4 loads
        // mapped so each set of 8 lanes covers 128 contiguous bytes.
        #pragma unroll
        for (int l = 0; l < 4; ++l) {
            const int idx = tid + l * 256;      // 0..1023
            const int m   = idx >> 3;           // 0..127
            const int j   = idx & 7;            // 0..7
            const float* src = x + (size_t)(row0 + m) * kD + k0 + j * 4;
            const float4 v0 = *(const float4*)(src);
            const float4 v1 = *(const float4*)(src + 32);
            s16x4 p0, p1;
            p0[0] = f2bf(v0.x); p0[1] = f2bf(v0.y); p0[2] = f2bf(v0.z); p0[3] = f2bf(v0.w);
            p1[0] = f2bf(v1.x); p1[1] = f2bf(v1.y); p1[2] = f2bf(v1.z); p1[3] = f2bf(v1.w);
            *(s16x4*)&Xs[m][j * 4]      = p0;
            *(s16x4*)&Xs[m][j * 4 + 32] = p1;
        }
        // ---- stage Wz, Wh tiles: 64 rows x 64 k each
        #pragma unroll
        for (int l = 0; l < 2; ++l) {
            const int idx = tid + l * 256;      // 0..511
            const int m   = idx >> 3;           // 0..63
            const int j   = idx & 7;
            {
                const float* src = Wz + (size_t)(col0 + m) * kD + k0 + j * 4;
                const float4 v0 = *(const float4*)(src);
                const float4 v1 = *(const float4*)(src + 32);
                s16x4 p0, p1;
                p0[0] = f2bf(v0.x); p0[1] = f2bf(v0.y); p0[2] = f2bf(v0.z); p0[3] = f2bf(v0.w);
                p1[0] = f2bf(v1.x); p1[1] = f2bf(v1.y); p1[2] = f2bf(v1.z); p1[3] = f2bf(v1.w);
                *(s16x4*)&Wzs[m][j * 4]      = p0;
                *(s16x4*)&Wzs[m][j * 4 + 32] = p1;
            }
            {
                const float* src = Wh + (size_t)(col0 + m) * kD + k0 + j * 4;
                const float4 v0 = *(const float4*)(src);
                const float4 v1 = *(const float4*)(src + 32);
                s16x4 p0, p1;
                p0[0] = f2bf(v0.x); p0[1] = f2bf(v0.y); p0[2] = f2bf(v0.z); p0[3] = f2bf(v0.w);
                p1[0] = f2bf(v1.x); p1[1] = f2bf(v1.y); p1[2] = f2bf(v1.z); p1[3] = f2bf(v1.w);
                *(s16x4*)&Whs[m][j * 4]      = p0;
                *(s16x4*)&Whs[m][j * 4 + 32] = p1;
            }
        }
        __syncthreads();

        // ---- MFMA over this k tile (two K=32 chunks)
        #pragma unroll
        for (int kk = 0; kk < BK; kk += 32) {
            s16x8 af[4], bzf[2], buf[2];
            #pragma unroll
            for (int mt = 0; mt < 4; ++mt)
                af[mt] = *(const s16x8*)&Xs[wr0 + mt * 16 + ln15][kk + quad * 8];
            #pragma unroll
            for (int nt = 0; nt < 2; ++nt) {
                bzf[nt] = *(const s16x8*)&Wzs[wc0 + nt * 16 + ln15][kk + quad * 8];
                buf[nt] = *(const s16x8*)&Whs[wc0 + nt * 16 + ln15][kk + quad * 8];
            }
            #pragma unroll
            for (int mt = 0; mt < 4; ++mt) {
                #pragma unroll
                for (int nt = 0; nt < 2; ++nt) {
                    accZ[mt][nt] = __builtin_amdgcn_mfma_f32_16x16x32_bf16(
                        af[mt], bzf[nt], accZ[mt][nt], 0, 0, 0);
                    accU[mt][nt] = __builtin_amdgcn_mfma_f32_16x16x32_bf16(
                        af[mt], buf[nt], accU[mt][nt], 0, 0, 0);
                }
            }
        }
        __syncthreads();
    }

    // ---- epilogue: C/D layout col = lane&15, row = quad*4 + reg [m89]
    #pragma unroll
    for (int nt = 0; nt < 2; ++nt) {
        const int col = col0 + wc0 + nt * 16 + ln15;
        const float bzv = bz[col];
        const float bhv = bh[col];
        #pragma unroll
        for (int mt = 0; mt < 4; ++mt) {
            const int rb = row0 + wr0 + mt * 16 + quad * 4;
            #pragma unroll
            for (int r = 0; r < 4; ++r) {
                const float z = accZ[mt][nt][r] + bzv;
                const float g = 1.0f / (1.0f + __expf(-z));
                const float u = accU[mt][nt][r] + bhv;
                const size_t o = (size_t)(rb + r) * kH + col;
                a_ws [o] = 1.0f - g;
                bb_ws[o] = g * u;
            }
        }
    }
}

// ---------------------------------------------------------------------------
// Kernel B: per-chunk affine composition. h_end = A*h_start + Bv over kL steps.
// ---------------------------------------------------------------------------
__global__ __launch_bounds__(256)
void chunk_scan(const float* __restrict__ a_ws,
                const float* __restrict__ bb_ws,
                float* __restrict__ Asum,
                float* __restrict__ Bsum)
{
    const int c = blockIdx.x % kNC;
    const int b = blockIdx.x / kNC;
    const int h = threadIdx.x;

    float A  = 1.0f;
    float Bv = 0.0f;
    const size_t base = ((size_t)b * kT + (size_t)c * kL) * kH + h;
    #pragma unroll 8
    for (int t = 0; t < kL; ++t) {
        const float a  = a_ws [base + (size_t)t * kH];
        const float bb = bb_ws[base + (size_t)t * kH];
        Bv = fmaf(a, Bv, bb);
        A *= a;
    }
    const size_t o = ((size_t)b * kNC + c) * kH + h;
    Asum[o] = A;
    Bsum[o] = Bv;
}

// ---------------------------------------------------------------------------
// Kernel C: sequential combine over chunk summaries -> h at each chunk start.
// ---------------------------------------------------------------------------
__global__ __launch_bounds__(256)
void chunk_combine(const float* __restrict__ h0,
                   const float* __restrict__ Asum,
                   const float* __restrict__ Bsum,
                   float* __restrict__ hstart)
{
    const int b = blockIdx.x;
    const int h = threadIdx.x;
    float hv = h0[(size_t)b * kH + h];
    #pragma unroll 8
    for (int c = 0; c < kNC; ++c) {
        const size_t idx = ((size_t)b * kNC + c) * kH + h;
        hstart[idx] = hv;
        hv = fmaf(Asum[idx], hv, Bsum[idx]);
    }
}

// ---------------------------------------------------------------------------
// Kernel D: apply recurrence within each chunk from its known h_start.
// ---------------------------------------------------------------------------
__global__ __launch_bounds__(256)
void apply_scan(const float* __restrict__ a_ws,
                const float* __restrict__ bb_ws,
                const float* __restrict__ hstart,
                float* __restrict__ out)
{
    const int c = blockIdx.x % kNC;
    const int b = blockIdx.x / kNC;
    const int h = threadIdx.x;

    float hv = hstart[((size_t)b * kNC + c) * kH + h];
    const size_t base = ((size_t)b * kT + (size_t)c * kL) * kH + h;
    #pragma unroll 8
    for (int t = 0; t < kL; ++t) {
        const float a  = a_ws [base + (size_t)t * kH];
        const float bb = bb_ws[base + (size_t)t * kH];
        hv = fmaf(a, hv, bb);
        out[base + (size_t)t * kH] = hv;
    }
}

extern "C" void kernel_launch(void* const* d_in, const int* in_sizes, int n_in,
                              void* d_out, int out_size, void* d_ws, size_t ws_size,
                              hipStream_t stream)
{
    const float* x  = (const float*)d_in[0];
    const float* h0 = (const float*)d_in[1];
    const float* Wz = (const float*)d_in[2];
    const float* bz = (const float*)d_in[3];
    const float* Wh = (const float*)d_in[4];
    const float* bh = (const float*)d_in[5];
    float* out = (float*)d_out;

    // Workspace: a(33.5MB) + bb(33.5MB) + Asum/Bsum/hstart (1MB each).
    float* a_ws   = (float*)d_ws;
    float* bb_ws  = a_ws  + (size_t)kBT * kH;
    float* Asum   = bb_ws + (size_t)kBT * kH;
    float* Bsum   = Asum  + (size_t)kB * kNC * kH;
    float* hstart = Bsum  + (size_t)kB * kNC * kH;

    gemm_gate_update<<<dim3(kH / TH, kBT / TM), 256, 0, stream>>>(
        x, Wz, bz, Wh, bh, a_ws, bb_ws);
    chunk_scan<<<kB * kNC, kH, 0, stream>>>(a_ws, bb_ws, Asum, Bsum);
    chunk_combine<<<kB, kH, 0, stream>>>(h0, Asum, Bsum, hstart);
    apply_scan<<<kB * kNC, kH, 0, stream>>>(a_ws, bb_ws, hstart, out);
}

// Round 3
// 132.046 us; speedup vs baseline: 1.6963x; 1.1616x over previous
//
#include <hip/hip_runtime.h>
#include <hip/hip_fp16.h>

// MinGRU fused pipeline, round 3.
// 1) convert_bf16: x, Wz, Wh fp32 -> bf16 (one pass; lets GEMM use
//    global_load_lds with zero staging VALU).
// 2) gemm_fused:   m97-style bf16 MFMA GEMM (128x64 tile, BK=64, dual-W),
//    fused sigmoid epilogue -> interleaved (a,bb) fp16 half2 + per-sub-chunk
//    (L=32) affine summaries computed through LDS (chunk_scan kernel removed).
// 3) combine:      sequential affine compose over 128 chunk summaries -> hstart.
// 4) apply:        per-chunk recurrence from hstart, writes fp32 output.

namespace {
constexpr int kB  = 8;
constexpr int kT  = 4096;
constexpr int kD  = 256;
constexpr int kH  = 256;
constexpr int kBT = kB * kT;
constexpr int kL  = 32;           // scan chunk length
constexpr int kNC = kT / kL;      // 128 chunks per sequence

constexpr int TM  = 128;          // GEMM row (time) tile
constexpr int TH  = 64;           // GEMM h tile (dual-W => 128 effective N)
constexpr int BK  = 64;           // GEMM k tile (bf16)
} // namespace

typedef short s16x8 __attribute__((ext_vector_type(8)));
typedef short s16x4 __attribute__((ext_vector_type(4)));
typedef float f32x4 __attribute__((ext_vector_type(4)));

__device__ __forceinline__ short f2bf(float f) {
    union { float f; unsigned int u; } v; v.f = f;
    unsigned int r = v.u + 0x7fffu + ((v.u >> 16) & 1u);   // RNE
    return (short)(r >> 16);
}

__device__ __forceinline__ void load_lds16(const void* g, void* l) {
    __builtin_amdgcn_global_load_lds(
        (const __attribute__((address_space(1))) void*)g,
        (__attribute__((address_space(3))) void*)l, 16, 0, 0);
}

// ---------------------------------------------------------------------------
// Kernel 1: fp32 -> bf16 conversion for x, Wz, Wh.
// ---------------------------------------------------------------------------
__global__ __launch_bounds__(256)
void convert_bf16(const float* __restrict__ x,
                  const float* __restrict__ Wz,
                  const float* __restrict__ Wh,
                  unsigned short* __restrict__ xb,
                  unsigned short* __restrict__ wzb,
                  unsigned short* __restrict__ whb)
{
    constexpr int X4 = kBT * kD / 4;   // 2,097,152 float4s
    constexpr int W4 = kH  * kD / 4;   // 16,384 each
    const int i = blockIdx.x * 256 + threadIdx.x;
    const float* src; unsigned short* dst; int j;
    if (i < X4)           { src = x;  dst = xb;  j = i; }
    else if (i < X4 + W4) { src = Wz; dst = wzb; j = i - X4; }
    else                  { src = Wh; dst = whb; j = i - X4 - W4; }
    const float4 v = ((const float4*)src)[j];
    s16x4 p;
    p[0] = f2bf(v.x); p[1] = f2bf(v.y); p[2] = f2bf(v.z); p[3] = f2bf(v.w);
    ((s16x4*)dst)[j] = p;
}

// ---------------------------------------------------------------------------
// Kernel 2: dual GEMM + sigmoid + (a,bb) half2 store + sub-chunk summaries.
// Grid: (kH/TH = 4, kBT/TM = 256). 4 waves/block.
// ---------------------------------------------------------------------------
__global__ __launch_bounds__(256)
void gemm_fused(const unsigned short* __restrict__ xb,
                const unsigned short* __restrict__ wzb,
                const unsigned short* __restrict__ whb,
                const float* __restrict__ bz,
                const float* __restrict__ bh,
                __half2* __restrict__ ab_ws,     // [kBT][kH] (a,bb)
                float2* __restrict__ ABsum)      // [kB*kNC][kH] (A,Bv)
{
    // 32 KB: staging (Xs 16K | Wzs 8K | Whs 8K) overlaid by summary
    // (a_lds 16K | b_lds 16K) after the K-loop's final barrier.
    __shared__ __align__(16) unsigned char smem[32768];
    unsigned short* Xs  = (unsigned short*)smem;     // [128][64] linear, no pad
    unsigned short* Wzs = Xs  + 128 * 64;            // [64][64]
    unsigned short* Whs = Wzs + 64 * 64;             // [64][64]
    __half* a_lds = (__half*)smem;                   // [128][64]
    __half* b_lds = a_lds + 128 * 64;                // [128][64]

    const int tid  = threadIdx.x;
    const int lane = tid & 63;
    const int wv   = tid >> 6;
    const int ln15 = lane & 15;
    const int quad = lane >> 4;
    const int wr0  = (wv & 1) * 64;     // wave row offset
    const int wc0  = (wv >> 1) * 32;    // wave h-col offset
    const int row0 = blockIdx.y * TM;
    const int col0 = blockIdx.x * TH;

    // per-lane global row/col for staging (8 rows per 1KB segment)
    const int srow = lane >> 3;         // 0..7
    const int sk   = (lane & 7) * 8;    // k element offset 0..56

    f32x4 accZ[4][2] = {};
    f32x4 accU[4][2] = {};

    for (int k0 = 0; k0 < kD; k0 += BK) {
        // ---- async stage: per wave 4 X-segments + 2 Wz + 2 Wh (1 KB each)
        #pragma unroll
        for (int s = 0; s < 4; ++s) {
            const int seg = wv * 4 + s;                  // 0..15
            const int m = seg * 8 + srow;                // 0..127
            load_lds16(xb + (size_t)(row0 + m) * kD + k0 + sk, Xs + seg * 512);
        }
        #pragma unroll
        for (int s = 0; s < 2; ++s) {
            const int seg = wv * 2 + s;                  // 0..7
            const int m = seg * 8 + srow;                // 0..63
            load_lds16(wzb + (size_t)(col0 + m) * kD + k0 + sk, Wzs + seg * 512);
            load_lds16(whb + (size_t)(col0 + m) * kD + k0 + sk, Whs + seg * 512);
        }
        __syncthreads();

        // ---- MFMA over this k tile (two K=32 chunks)
        #pragma unroll
        for (int kk = 0; kk < BK; kk += 32) {
            s16x8 af[4], bzf[2], buf[2];
            #pragma unroll
            for (int mt = 0; mt < 4; ++mt)
                af[mt] = *(const s16x8*)&Xs[(wr0 + mt * 16 + ln15) * 64 + kk + quad * 8];
            #pragma unroll
            for (int nt = 0; nt < 2; ++nt) {
                bzf[nt] = *(const s16x8*)&Wzs[(wc0 + nt * 16 + ln15) * 64 + kk + quad * 8];
                buf[nt] = *(const s16x8*)&Whs[(wc0 + nt * 16 + ln15) * 64 + kk + quad * 8];
            }
            #pragma unroll
            for (int mt = 0; mt < 4; ++mt) {
                #pragma unroll
                for (int nt = 0; nt < 2; ++nt) {
                    accZ[mt][nt] = __builtin_amdgcn_mfma_f32_16x16x32_bf16(
                        af[mt], bzf[nt], accZ[mt][nt], 0, 0, 0);
                    accU[mt][nt] = __builtin_amdgcn_mfma_f32_16x16x32_bf16(
                        af[mt], buf[nt], accU[mt][nt], 0, 0, 0);
                }
            }
        }
        __syncthreads();   // waves done with LDS before next stage / epilogue
    }

    // ---- epilogue: sigmoid, write a/bb halves to LDS (C/D: col=ln15, row=quad*4+r)
    #pragma unroll
    for (int nt = 0; nt < 2; ++nt) {
        const int col = col0 + wc0 + nt * 16 + ln15;
        const int lc  = wc0 + nt * 16 + ln15;
        const float bzv = bz[col];
        const float bhv = bh[col];
        #pragma unroll
        for (int mt = 0; mt < 4; ++mt) {
            const int rb = wr0 + mt * 16 + quad * 4;
            #pragma unroll
            for (int r = 0; r < 4; ++r) {
                const float z = accZ[mt][nt][r] + bzv;
                const float g = 1.0f / (1.0f + __expf(-z));
                const float u = accU[mt][nt][r] + bhv;
                a_lds[(rb + r) * 64 + lc] = __float2half_rn(1.0f - g);
                b_lds[(rb + r) * 64 + lc] = __float2half_rn(g * u);
            }
        }
    }
    __syncthreads();

    // ---- coalesced interleaved (a,bb) global write: 8 B per thread per iter
    #pragma unroll
    for (int it = 0; it < 16; ++it) {
        const int q  = tid + it * 256;        // half2-pair index, 0..4095
        const int t  = q >> 5;                // 0..127
        const int hp = (q & 31) * 2;          // 0,2,..,62
        const __half a0 = a_lds[t * 64 + hp],     a1 = a_lds[t * 64 + hp + 1];
        const __half b0 = b_lds[t * 64 + hp],     b1 = b_lds[t * 64 + hp + 1];
        __half2 v0, v1;
        v0 = __halves2half2(a0, b0);
        v1 = __halves2half2(a1, b1);
        __half2* dst = ab_ws + (size_t)(row0 + t) * kH + col0 + hp;
        dst[0] = v0; dst[1] = v1;
    }

    // ---- sub-chunk affine summaries: 4 sub-chunks x 64 h
    {
        const int s = tid >> 6;               // sub-chunk 0..3
        const int h = tid & 63;
        float A = 1.0f, Bv = 0.0f;
        #pragma unroll 8
        for (int t = s * 32; t < s * 32 + 32; ++t) {
            const float a  = __half2float(a_lds[t * 64 + h]);
            const float bb = __half2float(b_lds[t * 64 + h]);
            Bv = fmaf(a, Bv, bb);
            A *= a;
        }
        const int b = row0 / kT;
        const int c = (row0 % kT) / kL + s;
        float2 o; o.x = A; o.y = Bv;
        ABsum[(size_t)(b * kNC + c) * kH + col0 + h] = o;
    }
}

// ---------------------------------------------------------------------------
// Kernel 3: sequential combine over chunk summaries -> h at each chunk start.
// ---------------------------------------------------------------------------
__global__ __launch_bounds__(256)
void combine(const float* __restrict__ h0,
             const float2* __restrict__ ABsum,
             float* __restrict__ hstart)
{
    const int b = blockIdx.x;
    const int h = threadIdx.x;
    float hv = h0[(size_t)b * kH + h];
    #pragma unroll 8
    for (int c = 0; c < kNC; ++c) {
        const size_t idx = (size_t)(b * kNC + c) * kH + h;
        hstart[idx] = hv;
        const float2 ab = ABsum[idx];
        hv = fmaf(ab.x, hv, ab.y);
    }
}

// ---------------------------------------------------------------------------
// Kernel 4: apply recurrence within each chunk from its known h_start.
// ---------------------------------------------------------------------------
__global__ __launch_bounds__(256)
void apply_scan(const __half2* __restrict__ ab_ws,
                const float* __restrict__ hstart,
                float* __restrict__ out)
{
    const int c = blockIdx.x & (kNC - 1);
    const int b = blockIdx.x >> 7;            // kNC = 128
    const int h = threadIdx.x;

    float hv = hstart[(size_t)(b * kNC + c) * kH + h];
    const size_t base = ((size_t)b * kT + (size_t)c * kL) * kH + h;
    #pragma unroll 8
    for (int t = 0; t < kL; ++t) {
        const __half2 ab = ab_ws[base + (size_t)t * kH];
        hv = fmaf(__low2float(ab), hv, __high2float(ab));
        out[base + (size_t)t * kH] = hv;
    }
}

extern "C" void kernel_launch(void* const* d_in, const int* in_sizes, int n_in,
                              void* d_out, int out_size, void* d_ws, size_t ws_size,
                              hipStream_t stream)
{
    const float* x  = (const float*)d_in[0];
    const float* h0 = (const float*)d_in[1];
    const float* Wz = (const float*)d_in[2];
    const float* bz = (const float*)d_in[3];
    const float* Wh = (const float*)d_in[4];
    const float* bh = (const float*)d_in[5];
    float* out = (float*)d_out;

    // Workspace carve-up (bytes): xb 16.78M | wzb/whb 131K | ab 33.55M |
    // ABsum 2.10M | hstart 1.05M  => ~53.7 MB total.
    unsigned char* ws = (unsigned char*)d_ws;
    unsigned short* xb  = (unsigned short*)ws;                 ws += (size_t)kBT * kD * 2;
    unsigned short* wzb = (unsigned short*)ws;                 ws += (size_t)kH * kD * 2;
    unsigned short* whb = (unsigned short*)ws;                 ws += (size_t)kH * kD * 2;
    __half2* ab_ws      = (__half2*)ws;                        ws += (size_t)kBT * kH * 4;
    float2* ABsum       = (float2*)ws;                         ws += (size_t)kB * kNC * kH * 8;
    float* hstart       = (float*)ws;

    constexpr int CV_BLOCKS = (kBT * kD / 4 + 2 * (kH * kD / 4)) / 256;  // 8320
    convert_bf16<<<CV_BLOCKS, 256, 0, stream>>>(x, Wz, Wh, xb, wzb, whb);
    gemm_fused<<<dim3(kH / TH, kBT / TM), 256, 0, stream>>>(
        xb, wzb, whb, bz, bh, ab_ws, ABsum);
    combine<<<kB, kH, 0, stream>>>(h0, ABsum, hstart);
    apply_scan<<<kB * kNC, kH, 0, stream>>>(ab_ws, hstart, out);
}